// Round 1
// baseline (851.054 us; speedup 1.0000x reference)
//
#include <hip/hip_runtime.h>

#define NN 50000
#define CH 64

// ---------------- K1: dual projection  s = x@Ws + bs -> out, n = x@Wn + bn -> ws
// block = 256 threads = 4 waves; each wave handles 8 nodes, lane = output channel.
__global__ __launch_bounds__(256) void k1_proj(
    const float* __restrict__ x,
    const float* __restrict__ Wself, const float* __restrict__ bself,
    const float* __restrict__ Wneigh, const float* __restrict__ bneigh,
    float* __restrict__ sout, float* __restrict__ nout)
{
    __shared__ float ws[CH * CH];
    __shared__ float wn[CH * CH];
    const int tid = threadIdx.x;

    // cooperative staging of both 64x64 weight matrices (float4, coalesced)
    for (int i = tid * 4; i < CH * CH; i += 256 * 4) {
        *(float4*)&ws[i] = *(const float4*)&Wself[i];
        *(float4*)&wn[i] = *(const float4*)&Wneigh[i];
    }
    __syncthreads();

    const int lane = tid & 63;
    const int wave = tid >> 6;
    const int node0 = blockIdx.x * 32 + wave * 8;

    const float bs = bself[lane];
    const float bn = bneigh[lane];

    float accs[8], accn[8];
#pragma unroll
    for (int n = 0; n < 8; n++) { accs[n] = bs; accn[n] = bn; }

    // clamp load rows so the tail block never reads OOB (stores are guarded)
    size_t xoff[8];
#pragma unroll
    for (int n = 0; n < 8; n++) {
        int nidx = node0 + n; if (nidx > NN - 1) nidx = NN - 1;
        xoff[n] = (size_t)nidx * CH;
    }

    for (int k4 = 0; k4 < CH; k4 += 4) {
        float4 xv[8];
#pragma unroll
        for (int n = 0; n < 8; n++)
            xv[n] = *(const float4*)&x[xoff[n] + k4];
#pragma unroll
        for (int j = 0; j < 4; j++) {
            const float wsk = ws[(k4 + j) * CH + lane];
            const float wnk = wn[(k4 + j) * CH + lane];
#pragma unroll
            for (int n = 0; n < 8; n++) {
                const float xj = (j == 0) ? xv[n].x : (j == 1) ? xv[n].y
                               : (j == 2) ? xv[n].z : xv[n].w;
                accs[n] = fmaf(xj, wsk, accs[n]);
                accn[n] = fmaf(xj, wnk, accn[n]);
            }
        }
    }

#pragma unroll
    for (int n = 0; n < 8; n++) {
        const int nidx = node0 + n;
        if (nidx < NN) {
            sout[(size_t)nidx * CH + lane] = accs[n];
            nout[(size_t)nidx * CH + lane] = accn[n];
        }
    }
}

// ---------------- K2: edge scatter   out[col[e]] += n[row[e]]
// 16 threads per edge, each handles a float4 (4 channels).
__global__ __launch_bounds__(256) void k2_scatter(
    const int* __restrict__ rows, const int* __restrict__ cols,
    const float* __restrict__ nmsg, float* __restrict__ out, int E)
{
    const int t = blockIdx.x * 256 + threadIdx.x;
    const int e = t >> 4;
    if (e >= E) return;
    const int q = t & 15;

    const int r = rows[e];
    const int c = cols[e];

    const float4 v = *(const float4*)&nmsg[(size_t)r * CH + q * 4];
    float* dst = &out[(size_t)c * CH + q * 4];
    unsafeAtomicAdd(dst + 0, v.x);
    unsafeAtomicAdd(dst + 1, v.y);
    unsafeAtomicAdd(dst + 2, v.z);
    unsafeAtomicAdd(dst + 3, v.w);
}

// ---------------- K3: in-place ReLU on out (float4)
__global__ __launch_bounds__(256) void k3_relu(float* __restrict__ out, int n4)
{
    const int i = blockIdx.x * 256 + threadIdx.x;
    if (i < n4) {
        float4 v = ((float4*)out)[i];
        v.x = fmaxf(v.x, 0.f); v.y = fmaxf(v.y, 0.f);
        v.z = fmaxf(v.z, 0.f); v.w = fmaxf(v.w, 0.f);
        ((float4*)out)[i] = v;
    }
}

extern "C" void kernel_launch(void* const* d_in, const int* in_sizes, int n_in,
                              void* d_out, int out_size, void* d_ws, size_t ws_size,
                              hipStream_t stream)
{
    const float* x      = (const float*)d_in[0];
    const int*   edges  = (const int*)d_in[1];
    const float* Wself  = (const float*)d_in[2];
    const float* bself  = (const float*)d_in[3];
    const float* Wneigh = (const float*)d_in[4];
    const float* bneigh = (const float*)d_in[5];
    float* out = (float*)d_out;

    const int E = in_sizes[1] / 2;           // edge_index is [2, E]
    const int* rows = edges;                 // edge_index[0]
    const int* cols = edges + E;             // edge_index[1]

    float* nmsg = (float*)d_ws;              // 50000*64 floats = 12.8 MB

    // K1: projections. 32 nodes/block.
    const int b1 = (NN + 31) / 32;
    k1_proj<<<b1, 256, 0, stream>>>(x, Wself, bself, Wneigh, bneigh, out, nmsg);

    // K2: scatter-add over edges, 16 threads/edge.
    const int b2 = (E * 16 + 255) / 256;
    k2_scatter<<<b2, 256, 0, stream>>>(rows, cols, nmsg, out, E);

    // K3: ReLU.
    const int n4 = NN * CH / 4;
    const int b3 = (n4 + 255) / 256;
    k3_relu<<<b3, 256, 0, stream>>>(out, n4);
}

// Round 2
// 627.446 us; speedup vs baseline: 1.3564x; 1.3564x over previous
//
#include <hip/hip_runtime.h>

#define NN 50000
#define CH 64

// ---------- ws layout (bytes) ----------
// aggx : [0, 12.8MB)          float[NN*CH]  — sum of x rows per destination
// cnt  : [12.8MB, +200KB)     int[NN]       — in-degree
// off  : [13.0MB, +200KB)     int[NN]       — exclusive start offsets (mutated to end offsets by fill)
// list : [13.2MB, +3.2MB)     int[E]        — source node per edge, grouped by destination

// ---------------- K_hist: cnt[col[e]]++
__global__ __launch_bounds__(256) void k_hist(const int* __restrict__ cols,
                                              int* __restrict__ cnt, int E)
{
    int e = blockIdx.x * 256 + threadIdx.x;
    if (e < E) atomicAdd(&cnt[cols[e]], 1);
}

// ---------------- K_scan: off = exclusive_scan(cnt), single block of 1024
__global__ __launch_bounds__(1024) void k_scan(const int* __restrict__ cnt,
                                               int* __restrict__ off, int n)
{
    __shared__ int wsum[16];
    const int tid = threadIdx.x;
    const int lane = tid & 63, wid = tid >> 6;
    int carry = 0;
    for (int base = 0; base < n; base += 1024) {
        const int i = base + tid;
        const int v = (i < n) ? cnt[i] : 0;
        // wave-inclusive scan
        int s = v;
        #pragma unroll
        for (int d = 1; d < 64; d <<= 1) {
            int t = __shfl_up(s, d);
            if (lane >= d) s += t;
        }
        if (lane == 63) wsum[wid] = s;
        __syncthreads();
        if (wid == 0 && lane < 16) {
            int wscan = wsum[lane];
            #pragma unroll
            for (int d = 1; d < 16; d <<= 1) {
                int t = __shfl_up(wscan, d);
                if (lane >= d) wscan += t;
            }
            wsum[lane] = wscan;   // inclusive scan of wave sums
        }
        __syncthreads();
        const int wave_off = (wid == 0) ? 0 : wsum[wid - 1];
        if (i < n) off[i] = carry + wave_off + (s - v);  // exclusive
        carry += wsum[15];
        __syncthreads();          // protect wsum before next chunk
    }
}

// ---------------- K_fill: pos = off[col]++; list[pos] = row
__global__ __launch_bounds__(256) void k_fill(const int* __restrict__ rows,
                                              const int* __restrict__ cols,
                                              int* __restrict__ off,
                                              int* __restrict__ list, int E)
{
    int e = blockIdx.x * 256 + threadIdx.x;
    if (e < E) {
        const int pos = atomicAdd(&off[cols[e]], 1);
        list[pos] = rows[e];
    }
}

// ---------------- K_agg: aggx[c] = sum over incident edges of x[r]
// 16 threads per node (each owns one float4 of the 64 channels).
__global__ __launch_bounds__(256) void k_agg(const float* __restrict__ x,
                                             const int* __restrict__ off_end,
                                             const int* __restrict__ cnt,
                                             const int* __restrict__ list,
                                             float* __restrict__ aggx)
{
    const int t = blockIdx.x * 256 + threadIdx.x;
    const int node = t >> 4, q = t & 15;
    if (node >= NN) return;
    const int end = off_end[node];          // off was mutated to end offsets by k_fill
    const int start = end - cnt[node];
    float4 acc = {0.f, 0.f, 0.f, 0.f};
    for (int j = start; j < end; j++) {
        const int r = list[j];              // broadcast across the 16 lanes
        const float4 v = *(const float4*)&x[(size_t)r * CH + q * 4];
        acc.x += v.x; acc.y += v.y; acc.z += v.z; acc.w += v.w;
    }
    *(float4*)&aggx[(size_t)node * CH + q * 4] = acc;
}

// ---------------- K_fused: out = relu(x@Ws + bs + aggx@Wn + cnt*bn)
// 4 waves/block, 8 nodes/wave, lane = output channel.
__global__ __launch_bounds__(256) void k_fused(
    const float* __restrict__ x, const float* __restrict__ aggx,
    const int* __restrict__ cnt,
    const float* __restrict__ Wself, const float* __restrict__ bself,
    const float* __restrict__ Wneigh, const float* __restrict__ bneigh,
    float* __restrict__ out)
{
    __shared__ float ws[CH * CH];
    __shared__ float wn[CH * CH];
    const int tid = threadIdx.x;
    for (int i = tid * 4; i < CH * CH; i += 256 * 4) {
        *(float4*)&ws[i] = *(const float4*)&Wself[i];
        *(float4*)&wn[i] = *(const float4*)&Wneigh[i];
    }
    __syncthreads();

    const int lane = tid & 63;
    const int wave = tid >> 6;
    const int node0 = blockIdx.x * 32 + wave * 8;

    const float bsv = bself[lane];
    const float bnv = bneigh[lane];

    size_t roff[8];
    float acc[8];
#pragma unroll
    for (int n = 0; n < 8; n++) {
        int nd = node0 + n; if (nd > NN - 1) nd = NN - 1;   // clamp tail loads
        roff[n] = (size_t)nd * CH;
        acc[n] = bsv + (float)cnt[nd] * bnv;
    }

    for (int k4 = 0; k4 < CH; k4 += 4) {
        float4 xv[8], av[8];
#pragma unroll
        for (int n = 0; n < 8; n++) {
            xv[n] = *(const float4*)&x[roff[n] + k4];
            av[n] = *(const float4*)&aggx[roff[n] + k4];
        }
#pragma unroll
        for (int j = 0; j < 4; j++) {
            const float wsk = ws[(k4 + j) * CH + lane];
            const float wnk = wn[(k4 + j) * CH + lane];
#pragma unroll
            for (int n = 0; n < 8; n++) {
                const float xj = (j == 0) ? xv[n].x : (j == 1) ? xv[n].y
                               : (j == 2) ? xv[n].z : xv[n].w;
                const float aj = (j == 0) ? av[n].x : (j == 1) ? av[n].y
                               : (j == 2) ? av[n].z : av[n].w;
                acc[n] = fmaf(xj, wsk, acc[n]);
                acc[n] = fmaf(aj, wnk, acc[n]);
            }
        }
    }

#pragma unroll
    for (int n = 0; n < 8; n++) {
        const int nd = node0 + n;
        if (nd < NN)
            out[(size_t)nd * CH + lane] = fmaxf(acc[n], 0.f);
    }
}

extern "C" void kernel_launch(void* const* d_in, const int* in_sizes, int n_in,
                              void* d_out, int out_size, void* d_ws, size_t ws_size,
                              hipStream_t stream)
{
    const float* x      = (const float*)d_in[0];
    const int*   edges  = (const int*)d_in[1];
    const float* Wself  = (const float*)d_in[2];
    const float* bself  = (const float*)d_in[3];
    const float* Wneigh = (const float*)d_in[4];
    const float* bneigh = (const float*)d_in[5];
    float* out = (float*)d_out;

    const int E = in_sizes[1] / 2;
    const int* rows = edges;        // edge_index[0] (sources)
    const int* cols = edges + E;    // edge_index[1] (destinations)

    char* ws_base = (char*)d_ws;
    float* aggx = (float*)(ws_base);                       // 12.8 MB
    int*   cnt  = (int*)(ws_base + 12800000);              // 200 KB
    int*   off  = (int*)(ws_base + 13000000);              // 200 KB
    int*   list = (int*)(ws_base + 13200000);              // 3.2 MB

    hipMemsetAsync(cnt, 0, NN * sizeof(int), stream);

    const int bE = (E + 255) / 256;
    k_hist<<<bE, 256, 0, stream>>>(cols, cnt, E);
    k_scan<<<1, 1024, 0, stream>>>(cnt, off, NN);
    k_fill<<<bE, 256, 0, stream>>>(rows, cols, off, list, E);

    const int bA = (NN * 16 + 255) / 256;
    k_agg<<<bA, 256, 0, stream>>>(x, off, cnt, list, aggx);

    const int bF = (NN + 31) / 32;
    k_fused<<<bF, 256, 0, stream>>>(x, aggx, cnt, Wself, bself, Wneigh, bneigh, out);
}

// Round 3
// 225.618 us; speedup vs baseline: 3.7721x; 2.7810x over previous
//
#include <hip/hip_runtime.h>

#define NN 50000
#define CH 64

// ---------- ws layout (bytes) ----------
// aggx : [0, 12.8MB)          float[NN*CH]  — sum of x rows per destination
// cnt  : [12.8MB, +200KB)     int[NN]       — in-degree
// off  : [13.0MB, +200KB)     int[NN]       — exclusive start offsets (mutated to end by k_fill)
// list : [13.2MB, +3.2MB)     int[E]        — source node per edge, grouped by destination

// ---------------- K_hist: cnt[col[e]]++
__global__ __launch_bounds__(256) void k_hist(const int* __restrict__ cols,
                                              int* __restrict__ cnt, int E)
{
    int e = blockIdx.x * 256 + threadIdx.x;
    if (e < E) atomicAdd(&cnt[cols[e]], 1);
}

// ---------------- K_scan: off = exclusive_scan(cnt), single block of 1024
__global__ __launch_bounds__(1024) void k_scan(const int* __restrict__ cnt,
                                               int* __restrict__ off, int n)
{
    __shared__ int wsum[16];
    const int tid = threadIdx.x;
    const int lane = tid & 63, wid = tid >> 6;
    int carry = 0;
    for (int base = 0; base < n; base += 1024) {
        const int i = base + tid;
        const int v = (i < n) ? cnt[i] : 0;
        int s = v;
        #pragma unroll
        for (int d = 1; d < 64; d <<= 1) {
            int t = __shfl_up(s, d);
            if (lane >= d) s += t;
        }
        if (lane == 63) wsum[wid] = s;
        __syncthreads();
        if (wid == 0 && lane < 16) {
            int wscan = wsum[lane];
            #pragma unroll
            for (int d = 1; d < 16; d <<= 1) {
                int t = __shfl_up(wscan, d);
                if (lane >= d) wscan += t;
            }
            wsum[lane] = wscan;
        }
        __syncthreads();
        const int wave_off = (wid == 0) ? 0 : wsum[wid - 1];
        if (i < n) off[i] = carry + wave_off + (s - v);
        carry += wsum[15];
        __syncthreads();
    }
}

// ---------------- K_fill: pos = off[col]++; list[pos] = row
__global__ __launch_bounds__(256) void k_fill(const int* __restrict__ rows,
                                              const int* __restrict__ cols,
                                              int* __restrict__ off,
                                              int* __restrict__ list, int E)
{
    int e = blockIdx.x * 256 + threadIdx.x;
    if (e < E) {
        const int pos = atomicAdd(&off[cols[e]], 1);
        list[pos] = rows[e];
    }
}

// ---------------- K_agg: aggx[c] = sum over incident edges of x[r]
// 16 threads per node (each owns one float4 of the 64 channels).
__global__ __launch_bounds__(256) void k_agg(const float* __restrict__ x,
                                             const int* __restrict__ off_end,
                                             const int* __restrict__ cnt,
                                             const int* __restrict__ list,
                                             float* __restrict__ aggx)
{
    const int t = blockIdx.x * 256 + threadIdx.x;
    const int node = t >> 4, q = t & 15;
    if (node >= NN) return;
    const int end = off_end[node];
    const int start = end - cnt[node];
    float4 acc = {0.f, 0.f, 0.f, 0.f};
    for (int j = start; j < end; j++) {
        const int r = list[j];
        const float4 v = *(const float4*)&x[(size_t)r * CH + q * 4];
        acc.x += v.x; acc.y += v.y; acc.z += v.z; acc.w += v.w;
    }
    *(float4*)&aggx[(size_t)node * CH + q * 4] = acc;
}

// ---------------- K_fused: out = relu(x@Ws + bs + aggx@Wn + cnt*bn)
// 4 waves/block, 8 nodes/wave, lane = output channel.
// Register-lean: two sequential K-passes (self then neigh) so only one
// 8x float4 load batch is live at a time; int offsets; unroll pinned.
__global__ __launch_bounds__(256) void k_fused(
    const float* __restrict__ x, const float* __restrict__ aggx,
    const int* __restrict__ cnt,
    const float* __restrict__ Wself, const float* __restrict__ bself,
    const float* __restrict__ Wneigh, const float* __restrict__ bneigh,
    float* __restrict__ out)
{
    __shared__ float ws[CH * CH];
    __shared__ float wn[CH * CH];
    const int tid = threadIdx.x;
    for (int i = tid * 4; i < CH * CH; i += 256 * 4) {
        *(float4*)&ws[i] = *(const float4*)&Wself[i];
        *(float4*)&wn[i] = *(const float4*)&Wneigh[i];
    }
    __syncthreads();

    const int lane = tid & 63;
    const int wave = tid >> 6;
    const int node0 = blockIdx.x * 32 + wave * 8;

    const float bsv = bself[lane];
    const float bnv = bneigh[lane];

    int base[8];
    float acc[8];
#pragma unroll
    for (int n = 0; n < 8; n++) {
        int nd = node0 + n; if (nd > NN - 1) nd = NN - 1;   // clamp tail loads
        base[n] = nd * CH;
        acc[n] = bsv + (float)cnt[nd] * bnv;
    }

    // ---- pass 1: acc += x @ Wself
#pragma unroll 1
    for (int k4 = 0; k4 < CH; k4 += 4) {
        float4 xv[8];
#pragma unroll
        for (int n = 0; n < 8; n++)
            xv[n] = *(const float4*)&x[base[n] + k4];
#pragma unroll
        for (int j = 0; j < 4; j++) {
            const float wsk = ws[(k4 + j) * CH + lane];
#pragma unroll
            for (int n = 0; n < 8; n++) {
                const float xj = (j == 0) ? xv[n].x : (j == 1) ? xv[n].y
                               : (j == 2) ? xv[n].z : xv[n].w;
                acc[n] = fmaf(xj, wsk, acc[n]);
            }
        }
    }

    // ---- pass 2: acc += aggx @ Wneigh
#pragma unroll 1
    for (int k4 = 0; k4 < CH; k4 += 4) {
        float4 av[8];
#pragma unroll
        for (int n = 0; n < 8; n++)
            av[n] = *(const float4*)&aggx[base[n] + k4];
#pragma unroll
        for (int j = 0; j < 4; j++) {
            const float wnk = wn[(k4 + j) * CH + lane];
#pragma unroll
            for (int n = 0; n < 8; n++) {
                const float aj = (j == 0) ? av[n].x : (j == 1) ? av[n].y
                               : (j == 2) ? av[n].z : av[n].w;
                acc[n] = fmaf(aj, wnk, acc[n]);
            }
        }
    }

#pragma unroll
    for (int n = 0; n < 8; n++) {
        const int nd = node0 + n;
        if (nd < NN)
            out[(size_t)nd * CH + lane] = fmaxf(acc[n], 0.f);
    }
}

extern "C" void kernel_launch(void* const* d_in, const int* in_sizes, int n_in,
                              void* d_out, int out_size, void* d_ws, size_t ws_size,
                              hipStream_t stream)
{
    const float* x      = (const float*)d_in[0];
    const int*   edges  = (const int*)d_in[1];
    const float* Wself  = (const float*)d_in[2];
    const float* bself  = (const float*)d_in[3];
    const float* Wneigh = (const float*)d_in[4];
    const float* bneigh = (const float*)d_in[5];
    float* out = (float*)d_out;

    const int E = in_sizes[1] / 2;
    const int* rows = edges;        // edge_index[0] (sources)
    const int* cols = edges + E;    // edge_index[1] (destinations)

    char* ws_base = (char*)d_ws;
    float* aggx = (float*)(ws_base);                       // 12.8 MB
    int*   cnt  = (int*)(ws_base + 12800000);              // 200 KB
    int*   off  = (int*)(ws_base + 13000000);              // 200 KB
    int*   list = (int*)(ws_base + 13200000);              // 3.2 MB

    hipMemsetAsync(cnt, 0, NN * sizeof(int), stream);

    const int bE = (E + 255) / 256;
    k_hist<<<bE, 256, 0, stream>>>(cols, cnt, E);
    k_scan<<<1, 1024, 0, stream>>>(cnt, off, NN);
    k_fill<<<bE, 256, 0, stream>>>(rows, cols, off, list, E);

    const int bA = (NN * 16 + 255) / 256;
    k_agg<<<bA, 256, 0, stream>>>(x, off, cnt, list, aggx);

    const int bF = (NN + 31) / 32;
    k_fused<<<bF, 256, 0, stream>>>(x, aggx, cnt, Wself, bself, Wneigh, bneigh, out);
}

// Round 4
// 194.306 us; speedup vs baseline: 4.3800x; 1.1611x over previous
//
#include <hip/hip_runtime.h>

#define NN 50000
#define CH 64

// ---------- ws layout (bytes) ----------
// aggx : [0, 12.8MB)       float[NN*CH] — sum of x rows per destination
//        (first ~1KB aliased as bsum[] by the scan kernels, which all
//         complete before k_agg writes aggx — ordering-safe)
// cnt  : [12.8MB, +200KB)  int[NN]      — in-degree
// off  : [13.0MB, +200KB)  int[NN]      — start offsets (mutated to end by k_fill)
// list : [13.2MB, +3.2MB)  int[E]       — source node per edge, grouped by dest

// ---------------- K_hist: cnt[col[e]]++
__global__ __launch_bounds__(256) void k_hist(const int* __restrict__ cols,
                                              int* __restrict__ cnt, int E)
{
    int e = blockIdx.x * 256 + threadIdx.x;
    if (e < E) atomicAdd(&cnt[cols[e]], 1);
}

// ---------------- K_scan1: per-block (256-elem) exclusive scan + block sums
__global__ __launch_bounds__(256) void k_scan1(const int* __restrict__ cnt,
                                               int* __restrict__ off,
                                               int* __restrict__ bsum, int n)
{
    __shared__ int wsum[4];
    const int tid = threadIdx.x;
    const int lane = tid & 63, wid = tid >> 6;
    const int i = blockIdx.x * 256 + tid;
    const int v = (i < n) ? cnt[i] : 0;
    int s = v;
#pragma unroll
    for (int d = 1; d < 64; d <<= 1) {
        int t = __shfl_up(s, d);
        if (lane >= d) s += t;
    }
    if (lane == 63) wsum[wid] = s;
    __syncthreads();
    if (tid == 0) {
        int a = 0;
#pragma unroll
        for (int k = 0; k < 4; k++) { int t = wsum[k]; wsum[k] = a; a += t; }
        bsum[blockIdx.x] = a;
    }
    __syncthreads();
    if (i < n) off[i] = wsum[wid] + (s - v);   // block-local exclusive
}

// ---------------- K_scan2: single-wave exclusive scan of block sums (in place)
__global__ __launch_bounds__(64) void k_scan2(int* __restrict__ bsum, int nb)
{
    const int lane = threadIdx.x;
    int carry = 0;
    for (int base = 0; base < nb; base += 64) {
        const int i = base + lane;
        const int v = (i < nb) ? bsum[i] : 0;
        int s = v;
#pragma unroll
        for (int d = 1; d < 64; d <<= 1) {
            int t = __shfl_up(s, d);
            if (lane >= d) s += t;
        }
        if (i < nb) bsum[i] = carry + s - v;   // exclusive
        carry += __shfl(s, 63);
    }
}

// ---------------- K_scan3: add block offset back
__global__ __launch_bounds__(256) void k_scan3(int* __restrict__ off,
                                               const int* __restrict__ bsum, int n)
{
    const int i = blockIdx.x * 256 + threadIdx.x;
    if (i < n) off[i] += bsum[blockIdx.x];
}

// ---------------- K_fill: pos = off[col]++; list[pos] = row
__global__ __launch_bounds__(256) void k_fill(const int* __restrict__ rows,
                                              const int* __restrict__ cols,
                                              int* __restrict__ off,
                                              int* __restrict__ list, int E)
{
    int e = blockIdx.x * 256 + threadIdx.x;
    if (e < E) {
        const int pos = atomicAdd(&off[cols[e]], 1);
        list[pos] = rows[e];
    }
}

// ---------------- K_agg: aggx[c] = sum over incident edges of x[r]
// 16 threads per node (each owns one float4); start from off_end[node-1].
__global__ __launch_bounds__(256) void k_agg(const float* __restrict__ x,
                                             const int* __restrict__ off_end,
                                             const int* __restrict__ list,
                                             float* __restrict__ aggx)
{
    const int t = blockIdx.x * 256 + threadIdx.x;
    const int node = t >> 4, q = t & 15;
    if (node >= NN) return;
    const int end = off_end[node];
    const int start = (node == 0) ? 0 : off_end[node - 1];
    float4 a0 = {0.f, 0.f, 0.f, 0.f};
    float4 a1 = {0.f, 0.f, 0.f, 0.f};
    int j = start;
    for (; j + 1 < end; j += 2) {
        const int r0 = list[j], r1 = list[j + 1];
        const float4 v0 = *(const float4*)&x[(size_t)r0 * CH + q * 4];
        const float4 v1 = *(const float4*)&x[(size_t)r1 * CH + q * 4];
        a0.x += v0.x; a0.y += v0.y; a0.z += v0.z; a0.w += v0.w;
        a1.x += v1.x; a1.y += v1.y; a1.z += v1.z; a1.w += v1.w;
    }
    if (j < end) {
        const int r = list[j];
        const float4 v = *(const float4*)&x[(size_t)r * CH + q * 4];
        a0.x += v.x; a0.y += v.y; a0.z += v.z; a0.w += v.w;
    }
    a0.x += a1.x; a0.y += a1.y; a0.z += a1.z; a0.w += a1.w;
    *(float4*)&aggx[(size_t)node * CH + q * 4] = a0;
}

// ---------------- K_fused: out = relu(x@Ws + bs + aggx@Wn + cnt*bn)
// 512 threads = 8 waves/block, 8 nodes/wave -> 64 nodes/block.
// 32KB LDS: 4 blocks/CU x 8 waves = 32 waves/CU (100% wave cap).
__global__ __launch_bounds__(512) void k_fused(
    const float* __restrict__ x, const float* __restrict__ aggx,
    const int* __restrict__ cnt,
    const float* __restrict__ Wself, const float* __restrict__ bself,
    const float* __restrict__ Wneigh, const float* __restrict__ bneigh,
    float* __restrict__ out)
{
    __shared__ float ws[CH * CH];
    __shared__ float wn[CH * CH];
    const int tid = threadIdx.x;
    for (int i = tid * 4; i < CH * CH; i += 512 * 4) {
        *(float4*)&ws[i] = *(const float4*)&Wself[i];
        *(float4*)&wn[i] = *(const float4*)&Wneigh[i];
    }
    __syncthreads();

    const int lane = tid & 63;
    const int wave = tid >> 6;
    const int node0 = blockIdx.x * 64 + wave * 8;

    const float bsv = bself[lane];
    const float bnv = bneigh[lane];

    int base[8];
    float acc[8];
#pragma unroll
    for (int n = 0; n < 8; n++) {
        int nd = node0 + n; if (nd > NN - 1) nd = NN - 1;   // clamp tail loads
        base[n] = nd * CH;
        acc[n] = bsv + (float)cnt[nd] * bnv;
    }

    // merged pass: acc += x@Ws + aggx@Wn  (unroll pinned: keeps VGPR ~100)
#pragma unroll 1
    for (int k4 = 0; k4 < CH; k4 += 4) {
        float4 xv[8], av[8];
#pragma unroll
        for (int n = 0; n < 8; n++) {
            xv[n] = *(const float4*)&x[base[n] + k4];
            av[n] = *(const float4*)&aggx[base[n] + k4];
        }
#pragma unroll
        for (int j = 0; j < 4; j++) {
            const float wsk = ws[(k4 + j) * CH + lane];
            const float wnk = wn[(k4 + j) * CH + lane];
#pragma unroll
            for (int n = 0; n < 8; n++) {
                const float xj = (j == 0) ? xv[n].x : (j == 1) ? xv[n].y
                               : (j == 2) ? xv[n].z : xv[n].w;
                const float aj = (j == 0) ? av[n].x : (j == 1) ? av[n].y
                               : (j == 2) ? av[n].z : av[n].w;
                acc[n] = fmaf(xj, wsk, acc[n]);
                acc[n] = fmaf(aj, wnk, acc[n]);
            }
        }
    }

#pragma unroll
    for (int n = 0; n < 8; n++) {
        const int nd = node0 + n;
        if (nd < NN)
            out[(size_t)nd * CH + lane] = fmaxf(acc[n], 0.f);
    }
}

extern "C" void kernel_launch(void* const* d_in, const int* in_sizes, int n_in,
                              void* d_out, int out_size, void* d_ws, size_t ws_size,
                              hipStream_t stream)
{
    const float* x      = (const float*)d_in[0];
    const int*   edges  = (const int*)d_in[1];
    const float* Wself  = (const float*)d_in[2];
    const float* bself  = (const float*)d_in[3];
    const float* Wneigh = (const float*)d_in[4];
    const float* bneigh = (const float*)d_in[5];
    float* out = (float*)d_out;

    const int E = in_sizes[1] / 2;
    const int* rows = edges;        // edge_index[0] (sources)
    const int* cols = edges + E;    // edge_index[1] (destinations)

    char* ws_base = (char*)d_ws;
    float* aggx = (float*)(ws_base);                       // 12.8 MB
    int*   cnt  = (int*)(ws_base + 12800000);              // 200 KB
    int*   off  = (int*)(ws_base + 13000000);              // 200 KB
    int*   list = (int*)(ws_base + 13200000);              // 3.2 MB
    int*   bsum = (int*)(ws_base);                         // aliases aggx head; consumed before k_agg

    hipMemsetAsync(cnt, 0, NN * sizeof(int), stream);

    const int bE = (E + 255) / 256;
    const int bN = (NN + 255) / 256;                       // 196 blocks

    k_hist<<<bE, 256, 0, stream>>>(cols, cnt, E);
    k_scan1<<<bN, 256, 0, stream>>>(cnt, off, bsum, NN);
    k_scan2<<<1, 64, 0, stream>>>(bsum, bN);
    k_scan3<<<bN, 256, 0, stream>>>(off, bsum, NN);
    k_fill<<<bE, 256, 0, stream>>>(rows, cols, off, list, E);

    const int bA = (NN * 16 + 255) / 256;
    k_agg<<<bA, 256, 0, stream>>>(x, off, list, aggx);

    const int bF = (NN + 63) / 64;
    k_fused<<<bF, 512, 0, stream>>>(x, aggx, cnt, Wself, bself, Wneigh, bneigh, out);
}

// Round 5
// 151.538 us; speedup vs baseline: 5.6161x; 1.2822x over previous
//
#include <hip/hip_runtime.h>

#define NN 50000
#define CH 64

// ---------- ws layout (bytes) ----------
// m    : [0, 12.8MB)       float[NN*CH] — projected messages x@Wn + bn
//        (first ~1KB aliased as bsum[] by scan kernels; bsum fully consumed
//         by k_scan3/k_fill BEFORE k_proj writes m — stream-ordering safe)
// cnt  : [12.8MB, +200KB)  int[NN]      — in-degree
// off  : [13.0MB, +200KB)  int[NN]      — start offsets (mutated to end by k_fill)
// list : [13.2MB, +3.2MB)  int[E]       — source node per edge, grouped by dest

// ---------------- K_hist: cnt[col[e]]++
__global__ __launch_bounds__(256) void k_hist(const int* __restrict__ cols,
                                              int* __restrict__ cnt, int E)
{
    int e = blockIdx.x * 256 + threadIdx.x;
    if (e < E) atomicAdd(&cnt[cols[e]], 1);
}

// ---------------- K_scan1: per-block (256-elem) exclusive scan + block sums
__global__ __launch_bounds__(256) void k_scan1(const int* __restrict__ cnt,
                                               int* __restrict__ off,
                                               int* __restrict__ bsum, int n)
{
    __shared__ int wsum[4];
    const int tid = threadIdx.x;
    const int lane = tid & 63, wid = tid >> 6;
    const int i = blockIdx.x * 256 + tid;
    const int v = (i < n) ? cnt[i] : 0;
    int s = v;
#pragma unroll
    for (int d = 1; d < 64; d <<= 1) {
        int t = __shfl_up(s, d);
        if (lane >= d) s += t;
    }
    if (lane == 63) wsum[wid] = s;
    __syncthreads();
    if (tid == 0) {
        int a = 0;
#pragma unroll
        for (int k = 0; k < 4; k++) { int t = wsum[k]; wsum[k] = a; a += t; }
        bsum[blockIdx.x] = a;
    }
    __syncthreads();
    if (i < n) off[i] = wsum[wid] + (s - v);   // block-local exclusive
}

// ---------------- K_scan2: single-wave exclusive scan of block sums (in place)
__global__ __launch_bounds__(64) void k_scan2(int* __restrict__ bsum, int nb)
{
    const int lane = threadIdx.x;
    int carry = 0;
    for (int base = 0; base < nb; base += 64) {
        const int i = base + lane;
        const int v = (i < nb) ? bsum[i] : 0;
        int s = v;
#pragma unroll
        for (int d = 1; d < 64; d <<= 1) {
            int t = __shfl_up(s, d);
            if (lane >= d) s += t;
        }
        if (i < nb) bsum[i] = carry + s - v;   // exclusive
        carry += __shfl(s, 63);
    }
}

// ---------------- K_scan3: add block offset back
__global__ __launch_bounds__(256) void k_scan3(int* __restrict__ off,
                                               const int* __restrict__ bsum, int n)
{
    const int i = blockIdx.x * 256 + threadIdx.x;
    if (i < n) off[i] += bsum[blockIdx.x];
}

// ---------------- K_fill: pos = off[col]++; list[pos] = row
__global__ __launch_bounds__(256) void k_fill(const int* __restrict__ rows,
                                              const int* __restrict__ cols,
                                              int* __restrict__ off,
                                              int* __restrict__ list, int E)
{
    int e = blockIdx.x * 256 + threadIdx.x;
    if (e < E) {
        const int pos = atomicAdd(&off[cols[e]], 1);
        list[pos] = rows[e];
    }
}

// ---------------- K_proj: h = x@Ws + bs -> out,  m = x@Wn + bn -> ws.m
// 256 threads = 4 waves; 32 nodes/block staged in LDS via COALESCED loads;
// inner loop reads x fragments from LDS (broadcast, conflict-free) instead of
// wave-broadcast global loads (the round-3/4 latency killer).
__global__ __launch_bounds__(256) void k_proj(
    const float* __restrict__ x,
    const float* __restrict__ Wself, const float* __restrict__ bself,
    const float* __restrict__ Wneigh, const float* __restrict__ bneigh,
    float* __restrict__ hout, float* __restrict__ mout)
{
    __shared__ float ws[CH * CH];
    __shared__ float wn[CH * CH];
    __shared__ float xs[32 * CH];
    const int tid = threadIdx.x;
    const int node0 = blockIdx.x * 32;

    // stage weights: 4096 floats each, 256 thr x 4 iters x float4
    for (int i = tid * 4; i < CH * CH; i += 256 * 4) {
        *(float4*)&ws[i] = *(const float4*)&Wself[i];
        *(float4*)&wn[i] = *(const float4*)&Wneigh[i];
    }
    // stage x tile: 2048 floats, 2 iters, coalesced float4, zero-fill OOB rows
    for (int i = tid * 4; i < 32 * CH; i += 256 * 4) {
        const int nd = node0 + (i >> 6);
        float4 v = {0.f, 0.f, 0.f, 0.f};
        if (nd < NN) v = *(const float4*)&x[(size_t)nd * CH + (i & 63)];
        *(float4*)&xs[i] = v;
    }
    __syncthreads();

    const int lane = tid & 63;
    const int wave = tid >> 6;
    const int r0 = wave * 8;              // local row of this wave's 8 nodes

    const float bsv = bself[lane];
    const float bnv = bneigh[lane];

    float accs[8], accn[8];
#pragma unroll
    for (int n = 0; n < 8; n++) { accs[n] = bsv; accn[n] = bnv; }

#pragma unroll 1
    for (int k4 = 0; k4 < CH; k4 += 4) {
        float4 xv[8];
#pragma unroll
        for (int n = 0; n < 8; n++)
            xv[n] = *(const float4*)&xs[(r0 + n) * CH + k4];   // LDS broadcast
#pragma unroll
        for (int j = 0; j < 4; j++) {
            const float wsk = ws[(k4 + j) * CH + lane];
            const float wnk = wn[(k4 + j) * CH + lane];
#pragma unroll
            for (int n = 0; n < 8; n++) {
                const float xj = (j == 0) ? xv[n].x : (j == 1) ? xv[n].y
                               : (j == 2) ? xv[n].z : xv[n].w;
                accs[n] = fmaf(xj, wsk, accs[n]);
                accn[n] = fmaf(xj, wnk, accn[n]);
            }
        }
    }

#pragma unroll
    for (int n = 0; n < 8; n++) {
        const int nd = node0 + r0 + n;
        if (nd < NN) {
            hout[(size_t)nd * CH + lane] = accs[n];
            mout[(size_t)nd * CH + lane] = accn[n];
        }
    }
}

// ---------------- K_gfin: out[node] = relu(h[node] + sum_j m[list[j]])
// 16 threads per node (each owns one float4 of the 64 channels).
__global__ __launch_bounds__(256) void k_gfin(const float* __restrict__ m,
                                              const int* __restrict__ off_end,
                                              const int* __restrict__ list,
                                              float* __restrict__ out)
{
    const int t = blockIdx.x * 256 + threadIdx.x;
    const int node = t >> 4, q = t & 15;
    if (node >= NN) return;
    const int end = off_end[node];
    const int start = (node == 0) ? 0 : off_end[node - 1];

    float4 a0 = {0.f, 0.f, 0.f, 0.f};
    float4 a1 = {0.f, 0.f, 0.f, 0.f};
    int j = start;
    for (; j + 1 < end; j += 2) {
        const int r0v = list[j], r1v = list[j + 1];
        const float4 v0 = *(const float4*)&m[(size_t)r0v * CH + q * 4];
        const float4 v1 = *(const float4*)&m[(size_t)r1v * CH + q * 4];
        a0.x += v0.x; a0.y += v0.y; a0.z += v0.z; a0.w += v0.w;
        a1.x += v1.x; a1.y += v1.y; a1.z += v1.z; a1.w += v1.w;
    }
    if (j < end) {
        const int r = list[j];
        const float4 v = *(const float4*)&m[(size_t)r * CH + q * 4];
        a0.x += v.x; a0.y += v.y; a0.z += v.z; a0.w += v.w;
    }

    float4 h4 = *(const float4*)&out[(size_t)node * CH + q * 4];
    h4.x = fmaxf(h4.x + a0.x + a1.x, 0.f);
    h4.y = fmaxf(h4.y + a0.y + a1.y, 0.f);
    h4.z = fmaxf(h4.z + a0.z + a1.z, 0.f);
    h4.w = fmaxf(h4.w + a0.w + a1.w, 0.f);
    *(float4*)&out[(size_t)node * CH + q * 4] = h4;
}

extern "C" void kernel_launch(void* const* d_in, const int* in_sizes, int n_in,
                              void* d_out, int out_size, void* d_ws, size_t ws_size,
                              hipStream_t stream)
{
    const float* x      = (const float*)d_in[0];
    const int*   edges  = (const int*)d_in[1];
    const float* Wself  = (const float*)d_in[2];
    const float* bself  = (const float*)d_in[3];
    const float* Wneigh = (const float*)d_in[4];
    const float* bneigh = (const float*)d_in[5];
    float* out = (float*)d_out;

    const int E = in_sizes[1] / 2;
    const int* rows = edges;        // edge_index[0] (sources)
    const int* cols = edges + E;    // edge_index[1] (destinations)

    char* ws_base = (char*)d_ws;
    float* msg  = (float*)(ws_base);                       // 12.8 MB
    int*   cnt  = (int*)(ws_base + 12800000);              // 200 KB
    int*   off  = (int*)(ws_base + 13000000);              // 200 KB
    int*   list = (int*)(ws_base + 13200000);              // 3.2 MB
    int*   bsum = (int*)(ws_base);                         // aliases msg head; consumed before k_proj

    hipMemsetAsync(cnt, 0, NN * sizeof(int), stream);

    const int bE = (E + 255) / 256;
    const int bN = (NN + 255) / 256;                       // 196 blocks

    k_hist<<<bE, 256, 0, stream>>>(cols, cnt, E);
    k_scan1<<<bN, 256, 0, stream>>>(cnt, off, bsum, NN);
    k_scan2<<<1, 64, 0, stream>>>(bsum, bN);
    k_scan3<<<bN, 256, 0, stream>>>(off, bsum, NN);
    k_fill<<<bE, 256, 0, stream>>>(rows, cols, off, list, E);

    const int bP = (NN + 31) / 32;
    k_proj<<<bP, 256, 0, stream>>>(x, Wself, bself, Wneigh, bneigh, out, msg);

    const int bG = (NN * 16 + 255) / 256;
    k_gfin<<<bG, 256, 0, stream>>>(msg, off, list, out);
}

// Round 6
// 113.615 us; speedup vs baseline: 7.4907x; 1.3338x over previous
//
#include <hip/hip_runtime.h>

#define NN 50000
#define CH 64
#define NB 1563          // ceil(NN/32) coarse buckets of 32 nodes
#define NBLK 48          // blocks in coarse hist/scatter

// ---------- ws layout (bytes) ----------
// msg       : [0, 12.8MB)              float[NN*CH] — x@Wn + bn
// sorted    : [12.8M, 16.0M)           int[E] packed (dst&31)<<16 | src, grouped by bucket
// blockhist : [16.0M, +300,096)        int[NBLK][NB] counts -> exclusive per-block bases
// btotal    : [16,300,096, +6,252)     int[NB] bucket totals
// bstart    : [16,306,348, +6,256)     int[NB+1] bucket start offsets
// total 16,312,604 B  (< 16.4 MB proven available)

// ---------------- kc_hist: per-block LDS histogram of dest buckets (no global atomics)
__global__ __launch_bounds__(256) void kc_hist(const int* __restrict__ cols,
                                               int* __restrict__ bh, int E)
{
    __shared__ int lh[NB];
    const int b = blockIdx.x, tid = threadIdx.x;
    for (int k = tid; k < NB; k += 256) lh[k] = 0;
    __syncthreads();
    const int chunk = (E + NBLK - 1) / NBLK;
    const int beg = b * chunk;
    const int fin = min(beg + chunk, E);
    for (int i = beg + tid; i < fin; i += 256)
        atomicAdd(&lh[cols[i] >> 5], 1);
    __syncthreads();
    for (int k = tid; k < NB; k += 256) bh[b * NB + k] = lh[k];
}

// ---------------- kc_scanA: per-bucket exclusive prefix over blocks (in place) + totals
__global__ __launch_bounds__(256) void kc_scanA(int* __restrict__ bh,
                                                int* __restrict__ btotal)
{
    const int k = blockIdx.x * 256 + threadIdx.x;
    if (k >= NB) return;
    int run = 0;
    for (int b = 0; b < NBLK; b++) {
        const int t = bh[b * NB + k];
        bh[b * NB + k] = run;      // becomes this block's exclusive base within bucket k
        run += t;
    }
    btotal[k] = run;
}

// ---------------- kc_scanB: bstart = exclusive_scan(btotal); bstart[NB] = E
__global__ __launch_bounds__(1024) void kc_scanB(const int* __restrict__ cnt,
                                                 int* __restrict__ off, int n)
{
    __shared__ int wsum[16];
    const int tid = threadIdx.x;
    const int lane = tid & 63, wid = tid >> 6;
    int carry = 0;
    for (int base = 0; base < n; base += 1024) {
        const int i = base + tid;
        const int v = (i < n) ? cnt[i] : 0;
        int s = v;
#pragma unroll
        for (int d = 1; d < 64; d <<= 1) {
            int t = __shfl_up(s, d);
            if (lane >= d) s += t;
        }
        if (lane == 63) wsum[wid] = s;
        __syncthreads();
        if (wid == 0 && lane < 16) {
            int wscan = wsum[lane];
#pragma unroll
            for (int d = 1; d < 16; d <<= 1) {
                int t = __shfl_up(wscan, d);
                if (lane >= d) wscan += t;
            }
            wsum[lane] = wscan;
        }
        __syncthreads();
        const int wave_off = (wid == 0) ? 0 : wsum[wid - 1];
        if (i < n) off[i] = carry + wave_off + (s - v);
        carry += wsum[15];
        __syncthreads();
    }
    if (tid == 0) off[n] = carry;    // grand total = E
}

// ---------------- kc_scatter: place packed edges into bucket order; LDS atomics only
__global__ __launch_bounds__(256) void kc_scatter(
    const int* __restrict__ rows, const int* __restrict__ cols,
    const int* __restrict__ bh, const int* __restrict__ bstart,
    int* __restrict__ sorted, int E)
{
    __shared__ int lbase[NB];
    const int b = blockIdx.x, tid = threadIdx.x;
    for (int k = tid; k < NB; k += 256)
        lbase[k] = bstart[k] + bh[b * NB + k];
    __syncthreads();
    const int chunk = (E + NBLK - 1) / NBLK;
    const int beg = b * chunk;
    const int fin = min(beg + chunk, E);
    for (int i = beg + tid; i < fin; i += 256) {
        const int c = cols[i], r = rows[i];
        const int pos = atomicAdd(&lbase[c >> 5], 1);
        sorted[pos] = ((c & 31) << 16) | r;    // src < 50000 < 2^16
    }
}

// ---------------- k_proj: h = x@Ws + bs -> out,  m = x@Wn + bn -> msg
// (unchanged from round 5: LDS-staged x tile, broadcast LDS reads)
__global__ __launch_bounds__(256) void k_proj(
    const float* __restrict__ x,
    const float* __restrict__ Wself, const float* __restrict__ bself,
    const float* __restrict__ Wneigh, const float* __restrict__ bneigh,
    float* __restrict__ hout, float* __restrict__ mout)
{
    __shared__ float ws[CH * CH];
    __shared__ float wn[CH * CH];
    __shared__ float xs[32 * CH];
    const int tid = threadIdx.x;
    const int node0 = blockIdx.x * 32;

    for (int i = tid * 4; i < CH * CH; i += 256 * 4) {
        *(float4*)&ws[i] = *(const float4*)&Wself[i];
        *(float4*)&wn[i] = *(const float4*)&Wneigh[i];
    }
    for (int i = tid * 4; i < 32 * CH; i += 256 * 4) {
        const int nd = node0 + (i >> 6);
        float4 v = {0.f, 0.f, 0.f, 0.f};
        if (nd < NN) v = *(const float4*)&x[(size_t)nd * CH + (i & 63)];
        *(float4*)&xs[i] = v;
    }
    __syncthreads();

    const int lane = tid & 63;
    const int wave = tid >> 6;
    const int r0 = wave * 8;

    const float bsv = bself[lane];
    const float bnv = bneigh[lane];

    float accs[8], accn[8];
#pragma unroll
    for (int n = 0; n < 8; n++) { accs[n] = bsv; accn[n] = bnv; }

#pragma unroll 1
    for (int k4 = 0; k4 < CH; k4 += 4) {
        float4 xv[8];
#pragma unroll
        for (int n = 0; n < 8; n++)
            xv[n] = *(const float4*)&xs[(r0 + n) * CH + k4];
#pragma unroll
        for (int j = 0; j < 4; j++) {
            const float wsk = ws[(k4 + j) * CH + lane];
            const float wnk = wn[(k4 + j) * CH + lane];
#pragma unroll
            for (int n = 0; n < 8; n++) {
                const float xj = (j == 0) ? xv[n].x : (j == 1) ? xv[n].y
                               : (j == 2) ? xv[n].z : xv[n].w;
                accs[n] = fmaf(xj, wsk, accs[n]);
                accn[n] = fmaf(xj, wnk, accn[n]);
            }
        }
    }

#pragma unroll
    for (int n = 0; n < 8; n++) {
        const int nd = node0 + r0 + n;
        if (nd < NN) {
            hout[(size_t)nd * CH + lane] = accs[n];
            mout[(size_t)nd * CH + lane] = accn[n];
        }
    }
}

// ---------------- k_gfin2: one block per bucket (32 nodes).
// Fine counting-sort of the bucket's edges in LDS, then coalesced 256B row
// gathers of m; out = relu(h + sum). Chunked at 2048 for unconditional safety.
__global__ __launch_bounds__(256) void k_gfin2(
    const float* __restrict__ m, const int* __restrict__ bstart,
    const int* __restrict__ sorted, float* __restrict__ out)
{
    __shared__ int pairs[2048];
    __shared__ int srcs[2048];
    __shared__ int fh[32], foff[33], fcur[32];

    const int g = blockIdx.x;
    const int tid = threadIdx.x;
    const int lane = tid & 63, wave = tid >> 6;
    const int base = bstart[g];
    const int ecnt = bstart[g + 1] - base;

    float acc[8];
#pragma unroll
    for (int r = 0; r < 8; r++) acc[r] = 0.f;

    for (int cb = 0; cb < ecnt; cb += 2048) {
        const int cn = min(2048, ecnt - cb);
        if (tid < 32) fh[tid] = 0;
        __syncthreads();
        // stage + fine histogram (LDS atomics)
        for (int i = tid; i < cn; i += 256) {
            const int p = sorted[base + cb + i];
            pairs[i] = p;
            atomicAdd(&fh[p >> 16], 1);
        }
        __syncthreads();
        // 32-wide exclusive scan in wave 0
        if (tid < 64) {
            const int v = (lane < 32) ? fh[lane] : 0;
            int s = v;
#pragma unroll
            for (int d = 1; d < 32; d <<= 1) {
                int t = __shfl_up(s, d);
                if (lane >= d) s += t;
            }
            if (lane < 32) { foff[lane] = s - v; fcur[lane] = s - v; }
            if (lane == 0) foff[32] = cn;
        }
        __syncthreads();
        // fine scatter (LDS atomics)
        for (int i = tid; i < cn; i += 256) {
            const int p = pairs[i];
            const int pos = atomicAdd(&fcur[p >> 16], 1);
            srcs[pos] = p & 0xFFFF;
        }
        __syncthreads();
        // gather: wave handles 8 local nodes, lane = channel (256B coalesced rows)
#pragma unroll
        for (int r = 0; r < 8; r++) {
            const int nl = wave * 8 + r;
            const int j0 = foff[nl], j1 = foff[nl + 1];
            float a0 = 0.f, a1 = 0.f;
            int j = j0;
            for (; j + 1 < j1; j += 2) {
                a0 += m[srcs[j] * CH + lane];
                a1 += m[srcs[j + 1] * CH + lane];
            }
            if (j < j1) a0 += m[srcs[j] * CH + lane];
            acc[r] += a0 + a1;
        }
        __syncthreads();   // protect LDS before next chunk
    }

#pragma unroll
    for (int r = 0; r < 8; r++) {
        const int nd = g * 32 + wave * 8 + r;
        if (nd < NN) {
            const int o = nd * CH + lane;
            out[o] = fmaxf(out[o] + acc[r], 0.f);
        }
    }
}

extern "C" void kernel_launch(void* const* d_in, const int* in_sizes, int n_in,
                              void* d_out, int out_size, void* d_ws, size_t ws_size,
                              hipStream_t stream)
{
    const float* x      = (const float*)d_in[0];
    const int*   edges  = (const int*)d_in[1];
    const float* Wself  = (const float*)d_in[2];
    const float* bself  = (const float*)d_in[3];
    const float* Wneigh = (const float*)d_in[4];
    const float* bneigh = (const float*)d_in[5];
    float* out = (float*)d_out;

    const int E = in_sizes[1] / 2;
    const int* rows = edges;        // edge_index[0] (sources)
    const int* cols = edges + E;    // edge_index[1] (destinations)

    char* ws_base = (char*)d_ws;
    float* msg    = (float*)(ws_base);                     // 12.8 MB
    int*   sorted = (int*)(ws_base + 12800000);            // 3.2 MB
    int*   bh     = (int*)(ws_base + 16000000);            // NBLK*NB*4 = 300,096
    int*   btotal = (int*)(ws_base + 16300096);            // 6,252
    int*   bstart = (int*)(ws_base + 16306348);            // 6,256 (NB+1)

    kc_hist<<<NBLK, 256, 0, stream>>>(cols, bh, E);
    kc_scanA<<<(NB + 255) / 256, 256, 0, stream>>>(bh, btotal);
    kc_scanB<<<1, 1024, 0, stream>>>(btotal, bstart, NB);
    kc_scatter<<<NBLK, 256, 0, stream>>>(rows, cols, bh, bstart, sorted, E);

    const int bP = (NN + 31) / 32;   // 1563
    k_proj<<<bP, 256, 0, stream>>>(x, Wself, bself, Wneigh, bneigh, out, msg);

    k_gfin2<<<NB, 256, 0, stream>>>(msg, bstart, sorted, out);
}

// Round 7
// 96.118 us; speedup vs baseline: 8.8543x; 1.1820x over previous
//
#include <hip/hip_runtime.h>

#define NN 50000
#define CH 64
#define NB 1563          // ceil(NN/32) coarse buckets of 32 nodes
#define NBLK 128         // blocks in coarse hist/scatter

// ---------- ws layout (bytes) ----------
// msg       : [0, 12.8MB)              float[NN*CH] — x@Wn + bn
// sorted    : [12.8M, 16.0M)           int[E] packed (dst&31)<<16 | src, grouped by bucket
// blockhist : [16.0M, +800,256)        int[NBLK][NB] counts -> exclusive per-block bases
// btotal    : [16,800,256, +6,252)     int[NB] bucket totals
// bstart    : [16,806,508, +6,256)     int[NB+1] bucket start offsets

// ---------------- kc_hist: per-block LDS histogram of dest buckets (no global atomics)
__global__ __launch_bounds__(256) void kc_hist(const int* __restrict__ cols,
                                               int* __restrict__ bh, int E)
{
    __shared__ int lh[NB];
    const int b = blockIdx.x, tid = threadIdx.x;
    for (int k = tid; k < NB; k += 256) lh[k] = 0;
    __syncthreads();
    const int chunk = (E + NBLK - 1) / NBLK;
    const int beg = b * chunk;
    const int fin = min(beg + chunk, E);
    for (int i = beg + tid; i < fin; i += 256)
        atomicAdd(&lh[cols[i] >> 5], 1);
    __syncthreads();
    for (int k = tid; k < NB; k += 256) bh[b * NB + k] = lh[k];
}

// ---------------- kc_scanA: per-bucket exclusive prefix over blocks (in place) + totals
__global__ __launch_bounds__(256) void kc_scanA(int* __restrict__ bh,
                                                int* __restrict__ btotal)
{
    const int k = blockIdx.x * 256 + threadIdx.x;
    if (k >= NB) return;
    int run = 0;
#pragma unroll 4
    for (int b = 0; b < NBLK; b++) {
        const int t = bh[b * NB + k];
        bh[b * NB + k] = run;      // becomes this block's exclusive base within bucket k
        run += t;
    }
    btotal[k] = run;
}

// ---------------- kc_scanB: bstart = exclusive_scan(btotal); bstart[NB] = E
__global__ __launch_bounds__(1024) void kc_scanB(const int* __restrict__ cnt,
                                                 int* __restrict__ off, int n)
{
    __shared__ int wsum[16];
    const int tid = threadIdx.x;
    const int lane = tid & 63, wid = tid >> 6;
    int carry = 0;
    for (int base = 0; base < n; base += 1024) {
        const int i = base + tid;
        const int v = (i < n) ? cnt[i] : 0;
        int s = v;
#pragma unroll
        for (int d = 1; d < 64; d <<= 1) {
            int t = __shfl_up(s, d);
            if (lane >= d) s += t;
        }
        if (lane == 63) wsum[wid] = s;
        __syncthreads();
        if (wid == 0 && lane < 16) {
            int wscan = wsum[lane];
#pragma unroll
            for (int d = 1; d < 16; d <<= 1) {
                int t = __shfl_up(wscan, d);
                if (lane >= d) wscan += t;
            }
            wsum[lane] = wscan;
        }
        __syncthreads();
        const int wave_off = (wid == 0) ? 0 : wsum[wid - 1];
        if (i < n) off[i] = carry + wave_off + (s - v);
        carry += wsum[15];
        __syncthreads();
    }
    if (tid == 0) off[n] = carry;    // grand total = E
}

// ---------------- kc_scatter: place packed edges into bucket order; LDS atomics only
__global__ __launch_bounds__(256) void kc_scatter(
    const int* __restrict__ rows, const int* __restrict__ cols,
    const int* __restrict__ bh, const int* __restrict__ bstart,
    int* __restrict__ sorted, int E)
{
    __shared__ int lbase[NB];
    const int b = blockIdx.x, tid = threadIdx.x;
    for (int k = tid; k < NB; k += 256)
        lbase[k] = bstart[k] + bh[b * NB + k];
    __syncthreads();
    const int chunk = (E + NBLK - 1) / NBLK;
    const int beg = b * chunk;
    const int fin = min(beg + chunk, E);
    for (int i = beg + tid; i < fin; i += 256) {
        const int c = cols[i], r = rows[i];
        const int pos = atomicAdd(&lbase[c >> 5], 1);
        sorted[pos] = ((c & 31) << 16) | r;    // src < 50000 < 2^16
    }
}

// ---------------- k_proj: h = x@Ws + bs -> out,  m = x@Wn + bn -> msg
__global__ __launch_bounds__(256) void k_proj(
    const float* __restrict__ x,
    const float* __restrict__ Wself, const float* __restrict__ bself,
    const float* __restrict__ Wneigh, const float* __restrict__ bneigh,
    float* __restrict__ hout, float* __restrict__ mout)
{
    __shared__ float ws[CH * CH];
    __shared__ float wn[CH * CH];
    __shared__ float xs[32 * CH];
    const int tid = threadIdx.x;
    const int node0 = blockIdx.x * 32;

    for (int i = tid * 4; i < CH * CH; i += 256 * 4) {
        *(float4*)&ws[i] = *(const float4*)&Wself[i];
        *(float4*)&wn[i] = *(const float4*)&Wneigh[i];
    }
    for (int i = tid * 4; i < 32 * CH; i += 256 * 4) {
        const int nd = node0 + (i >> 6);
        float4 v = {0.f, 0.f, 0.f, 0.f};
        if (nd < NN) v = *(const float4*)&x[(size_t)nd * CH + (i & 63)];
        *(float4*)&xs[i] = v;
    }
    __syncthreads();

    const int lane = tid & 63;
    const int wave = tid >> 6;
    const int r0 = wave * 8;

    const float bsv = bself[lane];
    const float bnv = bneigh[lane];

    float accs[8], accn[8];
#pragma unroll
    for (int n = 0; n < 8; n++) { accs[n] = bsv; accn[n] = bnv; }

#pragma unroll 1
    for (int k4 = 0; k4 < CH; k4 += 4) {
        float4 xv[8];
#pragma unroll
        for (int n = 0; n < 8; n++)
            xv[n] = *(const float4*)&xs[(r0 + n) * CH + k4];
#pragma unroll
        for (int j = 0; j < 4; j++) {
            const float wsk = ws[(k4 + j) * CH + lane];
            const float wnk = wn[(k4 + j) * CH + lane];
#pragma unroll
            for (int n = 0; n < 8; n++) {
                const float xj = (j == 0) ? xv[n].x : (j == 1) ? xv[n].y
                               : (j == 2) ? xv[n].z : xv[n].w;
                accs[n] = fmaf(xj, wsk, accs[n]);
                accn[n] = fmaf(xj, wnk, accn[n]);
            }
        }
    }

#pragma unroll
    for (int n = 0; n < 8; n++) {
        const int nd = node0 + r0 + n;
        if (nd < NN) {
            hout[(size_t)nd * CH + lane] = accs[n];
            mout[(size_t)nd * CH + lane] = accn[n];
        }
    }
}

// ---------------- k_gfin2: one block per bucket (32 nodes), 512 threads = 8 waves.
// Fine counting-sort of the bucket's edges in LDS, then each wave gathers m rows
// for its 4 nodes with 4-deep MLP; out = relu(h + sum). Chunked at 2048.
__global__ __launch_bounds__(512) void k_gfin2(
    const float* __restrict__ m, const int* __restrict__ bstart,
    const int* __restrict__ sorted, float* __restrict__ out)
{
    __shared__ int pairs[2048];
    __shared__ int srcs[2048];
    __shared__ int fh[32], foff[33], fcur[32];

    const int g = blockIdx.x;
    const int tid = threadIdx.x;
    const int lane = tid & 63, wave = tid >> 6;
    const int base = bstart[g];
    const int ecnt = bstart[g + 1] - base;

    float acc[4];
#pragma unroll
    for (int r = 0; r < 4; r++) acc[r] = 0.f;

    for (int cb = 0; cb < ecnt; cb += 2048) {
        const int cn = min(2048, ecnt - cb);
        if (tid < 32) fh[tid] = 0;
        __syncthreads();
        // stage + fine histogram (LDS atomics)
        for (int i = tid; i < cn; i += 512) {
            const int p = sorted[base + cb + i];
            pairs[i] = p;
            atomicAdd(&fh[p >> 16], 1);
        }
        __syncthreads();
        // 32-wide exclusive scan in wave 0
        if (tid < 64) {
            const int v = (lane < 32) ? fh[lane] : 0;
            int s = v;
#pragma unroll
            for (int d = 1; d < 32; d <<= 1) {
                int t = __shfl_up(s, d);
                if (lane >= d) s += t;
            }
            if (lane < 32) { foff[lane] = s - v; fcur[lane] = s - v; }
            if (lane == 0) foff[32] = cn;
        }
        __syncthreads();
        // fine scatter (LDS atomics)
        for (int i = tid; i < cn; i += 512) {
            const int p = pairs[i];
            const int pos = atomicAdd(&fcur[p >> 16], 1);
            srcs[pos] = p & 0xFFFF;
        }
        __syncthreads();
        // gather: each wave handles 4 local nodes, lane = channel, 4-deep MLP
#pragma unroll
        for (int r = 0; r < 4; r++) {
            const int nl = wave * 4 + r;
            const int j0 = foff[nl], j1 = foff[nl + 1];
            float a0 = 0.f, a1 = 0.f, a2 = 0.f, a3 = 0.f;
            int j = j0;
            for (; j + 3 < j1; j += 4) {
                a0 += m[srcs[j]     * CH + lane];
                a1 += m[srcs[j + 1] * CH + lane];
                a2 += m[srcs[j + 2] * CH + lane];
                a3 += m[srcs[j + 3] * CH + lane];
            }
            for (; j < j1; j++)
                a0 += m[srcs[j] * CH + lane];
            acc[r] += (a0 + a1) + (a2 + a3);
        }
        __syncthreads();   // protect LDS before next chunk
    }

#pragma unroll
    for (int r = 0; r < 4; r++) {
        const int nd = g * 32 + wave * 4 + r;
        if (nd < NN) {
            const int o = nd * CH + lane;
            out[o] = fmaxf(out[o] + acc[r], 0.f);
        }
    }
}

extern "C" void kernel_launch(void* const* d_in, const int* in_sizes, int n_in,
                              void* d_out, int out_size, void* d_ws, size_t ws_size,
                              hipStream_t stream)
{
    const float* x      = (const float*)d_in[0];
    const int*   edges  = (const int*)d_in[1];
    const float* Wself  = (const float*)d_in[2];
    const float* bself  = (const float*)d_in[3];
    const float* Wneigh = (const float*)d_in[4];
    const float* bneigh = (const float*)d_in[5];
    float* out = (float*)d_out;

    const int E = in_sizes[1] / 2;
    const int* rows = edges;        // edge_index[0] (sources)
    const int* cols = edges + E;    // edge_index[1] (destinations)

    char* ws_base = (char*)d_ws;
    float* msg    = (float*)(ws_base);                     // 12.8 MB
    int*   sorted = (int*)(ws_base + 12800000);            // 3.2 MB
    int*   bh     = (int*)(ws_base + 16000000);            // NBLK*NB*4 = 800,256
    int*   btotal = (int*)(ws_base + 16800256);            // 6,252
    int*   bstart = (int*)(ws_base + 16806508);            // 6,256 (NB+1)

    kc_hist<<<NBLK, 256, 0, stream>>>(cols, bh, E);
    kc_scanA<<<(NB + 255) / 256, 256, 0, stream>>>(bh, btotal);
    kc_scanB<<<1, 1024, 0, stream>>>(btotal, bstart, NB);
    kc_scatter<<<NBLK, 256, 0, stream>>>(rows, cols, bh, bstart, sorted, E);

    const int bP = (NN + 31) / 32;   // 1563
    k_proj<<<bP, 256, 0, stream>>>(x, Wself, bself, Wneigh, bneigh, out, msg);

    k_gfin2<<<NB, 512, 0, stream>>>(msg, bstart, sorted, out);
}

// Round 8
// 93.984 us; speedup vs baseline: 9.0553x; 1.0227x over previous
//
#include <hip/hip_runtime.h>
#include <hip/hip_bf16.h>

#define NN 50000
#define CH 64
#define NB 1563          // ceil(NN/32) coarse buckets of 32 nodes
#define NBLK 128         // blocks in coarse hist/scatter

// ---------- ws layout (bytes) ----------
// msgb      : [0, 6.4MB)               uint[NN*32] — bf16x2-packed x@Wn + bn
// sorted    : [12.8M, 16.0M)           int[E] packed (dst&31)<<16 | src, grouped by bucket
// blockhist : [16.0M, +800,256)        int[NBLK][NB] counts -> exclusive per-block bases
// btotal    : [16,800,256, +6,252)     int[NB] bucket totals
// bstart    : [16,806,508, +6,256)     int[NB+1] bucket start offsets

// ---------------- kc_hist: per-block LDS histogram of dest buckets (no global atomics)
__global__ __launch_bounds__(256) void kc_hist(const int* __restrict__ cols,
                                               int* __restrict__ bh, int E)
{
    __shared__ int lh[NB];
    const int b = blockIdx.x, tid = threadIdx.x;
    for (int k = tid; k < NB; k += 256) lh[k] = 0;
    __syncthreads();
    const int chunk = (E + NBLK - 1) / NBLK;
    const int beg = b * chunk;
    const int fin = min(beg + chunk, E);
    for (int i = beg + tid; i < fin; i += 256)
        atomicAdd(&lh[cols[i] >> 5], 1);
    __syncthreads();
    for (int k = tid; k < NB; k += 256) bh[b * NB + k] = lh[k];
}

// ---------------- kc_scanA: per-bucket exclusive prefix over blocks (in place) + totals
__global__ __launch_bounds__(256) void kc_scanA(int* __restrict__ bh,
                                                int* __restrict__ btotal)
{
    const int k = blockIdx.x * 256 + threadIdx.x;
    if (k >= NB) return;
    int run = 0;
#pragma unroll 4
    for (int b = 0; b < NBLK; b++) {
        const int t = bh[b * NB + k];
        bh[b * NB + k] = run;
        run += t;
    }
    btotal[k] = run;
}

// ---------------- kc_scanB: bstart = exclusive_scan(btotal); bstart[NB] = E
__global__ __launch_bounds__(1024) void kc_scanB(const int* __restrict__ cnt,
                                                 int* __restrict__ off, int n)
{
    __shared__ int wsum[16];
    const int tid = threadIdx.x;
    const int lane = tid & 63, wid = tid >> 6;
    int carry = 0;
    for (int base = 0; base < n; base += 1024) {
        const int i = base + tid;
        const int v = (i < n) ? cnt[i] : 0;
        int s = v;
#pragma unroll
        for (int d = 1; d < 64; d <<= 1) {
            int t = __shfl_up(s, d);
            if (lane >= d) s += t;
        }
        if (lane == 63) wsum[wid] = s;
        __syncthreads();
        if (wid == 0 && lane < 16) {
            int wscan = wsum[lane];
#pragma unroll
            for (int d = 1; d < 16; d <<= 1) {
                int t = __shfl_up(wscan, d);
                if (lane >= d) wscan += t;
            }
            wsum[lane] = wscan;
        }
        __syncthreads();
        const int wave_off = (wid == 0) ? 0 : wsum[wid - 1];
        if (i < n) off[i] = carry + wave_off + (s - v);
        carry += wsum[15];
        __syncthreads();
    }
    if (tid == 0) off[n] = carry;
}

// ---------------- kc_scatter: place packed edges into bucket order; LDS atomics only
__global__ __launch_bounds__(256) void kc_scatter(
    const int* __restrict__ rows, const int* __restrict__ cols,
    const int* __restrict__ bh, const int* __restrict__ bstart,
    int* __restrict__ sorted, int E)
{
    __shared__ int lbase[NB];
    const int b = blockIdx.x, tid = threadIdx.x;
    for (int k = tid; k < NB; k += 256)
        lbase[k] = bstart[k] + bh[b * NB + k];
    __syncthreads();
    const int chunk = (E + NBLK - 1) / NBLK;
    const int beg = b * chunk;
    const int fin = min(beg + chunk, E);
    for (int i = beg + tid; i < fin; i += 256) {
        const int c = cols[i], r = rows[i];
        const int pos = atomicAdd(&lbase[c >> 5], 1);
        sorted[pos] = ((c & 31) << 16) | r;    // src < 50000 < 2^16
    }
}

// ---------------- k_proj: h = x@Ws + bs -> out (f32),  m = x@Wn + bn -> msgb (bf16x2)
__global__ __launch_bounds__(256) void k_proj(
    const float* __restrict__ x,
    const float* __restrict__ Wself, const float* __restrict__ bself,
    const float* __restrict__ Wneigh, const float* __restrict__ bneigh,
    float* __restrict__ hout, unsigned int* __restrict__ mout)
{
    __shared__ float ws[CH * CH];
    __shared__ float wn[CH * CH];
    __shared__ float xs[32 * CH];
    const int tid = threadIdx.x;
    const int node0 = blockIdx.x * 32;

    for (int i = tid * 4; i < CH * CH; i += 256 * 4) {
        *(float4*)&ws[i] = *(const float4*)&Wself[i];
        *(float4*)&wn[i] = *(const float4*)&Wneigh[i];
    }
    for (int i = tid * 4; i < 32 * CH; i += 256 * 4) {
        const int nd = node0 + (i >> 6);
        float4 v = {0.f, 0.f, 0.f, 0.f};
        if (nd < NN) v = *(const float4*)&x[(size_t)nd * CH + (i & 63)];
        *(float4*)&xs[i] = v;
    }
    __syncthreads();

    const int lane = tid & 63;
    const int wave = tid >> 6;
    const int r0 = wave * 8;

    const float bsv = bself[lane];
    const float bnv = bneigh[lane];

    float accs[8], accn[8];
#pragma unroll
    for (int n = 0; n < 8; n++) { accs[n] = bsv; accn[n] = bnv; }

#pragma unroll 1
    for (int k4 = 0; k4 < CH; k4 += 4) {
        float4 xv[8];
#pragma unroll
        for (int n = 0; n < 8; n++)
            xv[n] = *(const float4*)&xs[(r0 + n) * CH + k4];
#pragma unroll
        for (int j = 0; j < 4; j++) {
            const float wsk = ws[(k4 + j) * CH + lane];
            const float wnk = wn[(k4 + j) * CH + lane];
#pragma unroll
            for (int n = 0; n < 8; n++) {
                const float xj = (j == 0) ? xv[n].x : (j == 1) ? xv[n].y
                               : (j == 2) ? xv[n].z : xv[n].w;
                accs[n] = fmaf(xj, wsk, accs[n]);
                accn[n] = fmaf(xj, wnk, accn[n]);
            }
        }
    }

#pragma unroll
    for (int n = 0; n < 8; n++) {
        const int nd = node0 + r0 + n;
        // pair exchange: partner holds channel lane^1
        const float partner = __shfl_xor(accn[n], 1);
        if (nd < NN) {
            hout[(size_t)nd * CH + lane] = accs[n];
            if ((lane & 1) == 0) {
                // even lane: lo = own (ch lane), hi = partner (ch lane+1)
                __hip_bfloat162 p;
                p.x = __float2bfloat16(accn[n]);
                p.y = __float2bfloat16(partner);
                mout[(size_t)nd * 32 + (lane >> 1)] =
                    *reinterpret_cast<unsigned int*>(&p);
            }
        }
    }
}

// ---------------- k_gfin2: one block per bucket (32 nodes), 512 threads = 8 waves.
// Fine counting-sort in LDS, then gather of bf16x2 msg rows: the wave's two
// 32-lane halves process two edges at once (lane&31 = channel pair, lane>>5 =
// edge parity), 4-deep per half; cross-half shfl_xor reduce; out=relu(h+sum).
__global__ __launch_bounds__(512) void k_gfin2(
    const unsigned int* __restrict__ mb, const int* __restrict__ bstart,
    const int* __restrict__ sorted, float* __restrict__ out)
{
    __shared__ int pairs[2048];
    __shared__ unsigned short srcs[2048];
    __shared__ int fh[32], foff[33], fcur[32];

    const int g = blockIdx.x;
    const int tid = threadIdx.x;
    const int lane = tid & 63, wave = tid >> 6;
    const int c2 = lane & 31;        // channel-pair index
    const int half = lane >> 5;      // edge parity
    const int base = bstart[g];
    const int ecnt = bstart[g + 1] - base;

    float accL[4], accH[4];
#pragma unroll
    for (int r = 0; r < 4; r++) { accL[r] = 0.f; accH[r] = 0.f; }

    for (int cb = 0; cb < ecnt; cb += 2048) {
        const int cn = min(2048, ecnt - cb);
        if (tid < 32) fh[tid] = 0;
        __syncthreads();
        for (int i = tid; i < cn; i += 512) {
            const int p = sorted[base + cb + i];
            pairs[i] = p;
            atomicAdd(&fh[p >> 16], 1);
        }
        __syncthreads();
        if (tid < 64) {
            const int v = (lane < 32) ? fh[lane] : 0;
            int s = v;
#pragma unroll
            for (int d = 1; d < 32; d <<= 1) {
                int t = __shfl_up(s, d);
                if (lane >= d) s += t;
            }
            if (lane < 32) { foff[lane] = s - v; fcur[lane] = s - v; }
            if (lane == 0) foff[32] = cn;
        }
        __syncthreads();
        for (int i = tid; i < cn; i += 512) {
            const int p = pairs[i];
            const int pos = atomicAdd(&fcur[p >> 16], 1);
            srcs[pos] = (unsigned short)(p & 0xFFFF);
        }
        __syncthreads();
        // gather: wave handles 4 local nodes
#pragma unroll
        for (int r = 0; r < 4; r++) {
            const int nl = wave * 4 + r;
            const int j0 = foff[nl], j1 = foff[nl + 1];
            float l0 = 0.f, l1 = 0.f, l2 = 0.f, l3 = 0.f;
            float h0 = 0.f, h1 = 0.f, h2 = 0.f, h3 = 0.f;
            int j = j0 + half;
            for (; j + 6 < j1; j += 8) {
                const unsigned int v0 = mb[(int)srcs[j]     * 32 + c2];
                const unsigned int v1 = mb[(int)srcs[j + 2] * 32 + c2];
                const unsigned int v2 = mb[(int)srcs[j + 4] * 32 + c2];
                const unsigned int v3 = mb[(int)srcs[j + 6] * 32 + c2];
                l0 += __uint_as_float(v0 << 16); h0 += __uint_as_float(v0 & 0xFFFF0000u);
                l1 += __uint_as_float(v1 << 16); h1 += __uint_as_float(v1 & 0xFFFF0000u);
                l2 += __uint_as_float(v2 << 16); h2 += __uint_as_float(v2 & 0xFFFF0000u);
                l3 += __uint_as_float(v3 << 16); h3 += __uint_as_float(v3 & 0xFFFF0000u);
            }
            for (; j < j1; j += 2) {
                const unsigned int v = mb[(int)srcs[j] * 32 + c2];
                l0 += __uint_as_float(v << 16); h0 += __uint_as_float(v & 0xFFFF0000u);
            }
            accL[r] += (l0 + l1) + (l2 + l3);
            accH[r] += (h0 + h1) + (h2 + h3);
        }
        __syncthreads();   // protect LDS before next chunk
    }

    // cross-half reduce + write: half 0 -> even channel, half 1 -> odd channel
#pragma unroll
    for (int r = 0; r < 4; r++) {
        accL[r] += __shfl_xor(accL[r], 32);
        accH[r] += __shfl_xor(accH[r], 32);
        const int nd = g * 32 + wave * 4 + r;
        if (nd < NN) {
            const int o = nd * CH + 2 * c2 + half;
            const float myv = half ? accH[r] : accL[r];
            out[o] = fmaxf(out[o] + myv, 0.f);
        }
    }
}

extern "C" void kernel_launch(void* const* d_in, const int* in_sizes, int n_in,
                              void* d_out, int out_size, void* d_ws, size_t ws_size,
                              hipStream_t stream)
{
    const float* x      = (const float*)d_in[0];
    const int*   edges  = (const int*)d_in[1];
    const float* Wself  = (const float*)d_in[2];
    const float* bself  = (const float*)d_in[3];
    const float* Wneigh = (const float*)d_in[4];
    const float* bneigh = (const float*)d_in[5];
    float* out = (float*)d_out;

    const int E = in_sizes[1] / 2;
    const int* rows = edges;        // edge_index[0] (sources)
    const int* cols = edges + E;    // edge_index[1] (destinations)

    char* ws_base = (char*)d_ws;
    unsigned int* msgb = (unsigned int*)(ws_base);         // 6.4 MB (bf16x2)
    int*   sorted = (int*)(ws_base + 12800000);            // 3.2 MB
    int*   bh     = (int*)(ws_base + 16000000);            // NBLK*NB*4 = 800,256
    int*   btotal = (int*)(ws_base + 16800256);            // 6,252
    int*   bstart = (int*)(ws_base + 16806508);            // 6,256 (NB+1)

    kc_hist<<<NBLK, 256, 0, stream>>>(cols, bh, E);
    kc_scanA<<<(NB + 255) / 256, 256, 0, stream>>>(bh, btotal);
    kc_scanB<<<1, 1024, 0, stream>>>(btotal, bstart, NB);
    kc_scatter<<<NBLK, 256, 0, stream>>>(rows, cols, bh, bstart, sorted, E);

    const int bP = (NN + 31) / 32;   // 1563
    k_proj<<<bP, 256, 0, stream>>>(x, Wself, bself, Wneigh, bneigh, out, msgb);

    k_gfin2<<<NB, 512, 0, stream>>>(msgb, bstart, sorted, out);
}